// Round 1
// baseline (757.152 us; speedup 1.0000x reference)
//
#include <hip/hip_runtime.h>
#include <hip/hip_bf16.h>
#include <stdint.h>

// Problem constants (fixed by setup_inputs)
#define T_TOK   16384              // BS*L tokens
#define BSQ     8                  // sequences
#define MROWS   16392              // T + BS padded-buffer rows
#define MPAD    16512              // 129*128, M rounded to tile
#define NPADR   120                // MPAD - MROWS zero rows
#define K1      2048
#define N1      2048
#define H1      1024
#define K2      1024
#define N2      4096

typedef __attribute__((ext_vector_type(8))) short bf16x8;
typedef __attribute__((ext_vector_type(4))) float f32x4;

__device__ __forceinline__ void gll16(const void* g, void* l) {
  __builtin_amdgcn_global_load_lds(
      (const __attribute__((address_space(1))) void*)g,
      (__attribute__((address_space(3))) void*)l, 16, 0, 0);
}

// ---------------- transpose + f32->bf16 convert: out[C,R] = bf16(in[R,C]^T) --
__global__ __launch_bounds__(256) void transpose_cvt(
    const float* __restrict__ in, __hip_bfloat16* __restrict__ out,
    int R, int C) {
  __shared__ float tile[32][33];
  int bx = blockIdx.x * 32;   // col base in 'in'
  int by = blockIdx.y * 32;   // row base in 'in'
  int tx = threadIdx.x, ty = threadIdx.y;   // (32, 8)
  #pragma unroll
  for (int i = 0; i < 32; i += 8)
    tile[ty + i][tx] = in[(size_t)(by + ty + i) * C + bx + tx];
  __syncthreads();
  #pragma unroll
  for (int i = 0; i < 32; i += 8)
    out[(size_t)(bx + ty + i) * R + by + tx] = __float2bfloat16(tile[tx][ty + i]);
}

// ---------------- scatter tokens: xt[inputs_loc[t], :] = bf16(x[t, :]), 2048 cols
__global__ __launch_bounds__(256) void scatter_tokens(
    const float* __restrict__ x, const int* __restrict__ loc,
    __hip_bfloat16* __restrict__ xt) {
  int t = blockIdx.x;
  int c = threadIdx.x * 8;
  int r = loc[t];
  const float* src = x + (size_t)t * 2048 + c;
  float4 v0 = *(const float4*)src;
  float4 v1 = *(const float4*)(src + 4);
  union { __hip_bfloat16 h[8]; uint4 u; } o;
  o.h[0] = __float2bfloat16(v0.x); o.h[1] = __float2bfloat16(v0.y);
  o.h[2] = __float2bfloat16(v0.z); o.h[3] = __float2bfloat16(v0.w);
  o.h[4] = __float2bfloat16(v1.x); o.h[5] = __float2bfloat16(v1.y);
  o.h[6] = __float2bfloat16(v1.z); o.h[7] = __float2bfloat16(v1.w);
  *(uint4*)(xt + (size_t)r * 2048 + c) = o.u;
}

// ---------------- cache rows + zero pad rows -------------------------------
__global__ __launch_bounds__(256) void cachepad(
    const float* __restrict__ cache, const int* __restrict__ pre,
    const int* __restrict__ lfloc, __hip_bfloat16* __restrict__ xt, int cols) {
  int r = blockIdx.x;
  if (r < BSQ) {
    int dst = lfloc[r];
    const float* src = cache + (size_t)pre[r] * cols;
    for (int c = threadIdx.x; c < cols; c += 256)
      xt[(size_t)dst * cols + c] = __float2bfloat16(src[c]);
  } else {
    int dst = MROWS + (r - BSQ);
    for (int c = threadIdx.x; c < cols; c += 256)
      xt[(size_t)dst * cols + c] = __float2bfloat16(0.0f);
  }
}

// ---------------- m97-style bf16 MFMA GEMM: C[M,N] = A[M,K] * Bt[N,K]^T ----
// 128x128 tile, BK=32, 256 threads (4 waves 2x2), global_load_lds staging.
__global__ __launch_bounds__(256, 2) void gemm_bt(
    const __hip_bfloat16* __restrict__ A,
    const __hip_bfloat16* __restrict__ Bt,
    float* __restrict__ C, int N, int K) {
  __shared__ __align__(16) __hip_bfloat16 sA[128 * 32];
  __shared__ __align__(16) __hip_bfloat16 sB[128 * 32];
  const int tid = threadIdx.x;
  const int wave = tid >> 6, lane = tid & 63;
  const int wm = wave & 1, wn = wave >> 1;
  const int tn = blockIdx.x, tm = blockIdx.y;

  const __hip_bfloat16* Ab = A + (size_t)tm * 128 * K;
  const __hip_bfloat16* Bb = Bt + (size_t)tn * 128 * K;

  const int srow = wave * 16 + (lane >> 2);   // staging row within 64-row half
  const int scol = (lane & 3) * 8;            // staging col (bf16 elems)

  f32x4 acc[4][4];
  #pragma unroll
  for (int i = 0; i < 4; ++i)
    #pragma unroll
    for (int j = 0; j < 4; ++j)
      #pragma unroll
      for (int e = 0; e < 4; ++e) acc[i][j][e] = 0.0f;

  const int frow = lane & 15;        // fragment row/col within 16
  const int fk = (lane >> 4) * 8;    // fragment k offset

  for (int k0 = 0; k0 < K; k0 += 32) {
    // async global -> LDS, wave-uniform LDS base + lane*16B
    gll16(Ab + (size_t)srow * K + k0 + scol,        sA + (wave * 16) * 32);
    gll16(Ab + (size_t)(64 + srow) * K + k0 + scol, sA + (64 + wave * 16) * 32);
    gll16(Bb + (size_t)srow * K + k0 + scol,        sB + (wave * 16) * 32);
    gll16(Bb + (size_t)(64 + srow) * K + k0 + scol, sB + (64 + wave * 16) * 32);
    __builtin_amdgcn_s_waitcnt(0);
    __syncthreads();

    bf16x8 af[4], bfr[4];
    #pragma unroll
    for (int i = 0; i < 4; ++i)
      af[i] = *(const bf16x8*)(sA + (wm * 64 + i * 16 + frow) * 32 + fk);
    #pragma unroll
    for (int j = 0; j < 4; ++j)
      bfr[j] = *(const bf16x8*)(sB + (wn * 64 + j * 16 + frow) * 32 + fk);
    #pragma unroll
    for (int i = 0; i < 4; ++i)
      #pragma unroll
      for (int j = 0; j < 4; ++j)
        acc[i][j] = __builtin_amdgcn_mfma_f32_16x16x32_bf16(af[i], bfr[j], acc[i][j], 0, 0, 0);
    __syncthreads();
  }

  const int crow0 = tm * 128 + wm * 64 + (lane >> 4) * 4;
  const int ccol = tn * 128 + wn * 64 + (lane & 15);
  #pragma unroll
  for (int i = 0; i < 4; ++i)
    #pragma unroll
    for (int p = 0; p < 4; ++p) {
      float* dst = C + (size_t)(crow0 + i * 16 + p) * N + ccol;
      #pragma unroll
      for (int j = 0; j < 4; ++j) dst[j * 16] = acc[i][j][p];
    }
}

// ---------------- shift-add conv1 epilogue -> bf16 xt2 ---------------------
// o1[t,d] = c1[r,d] + c1[r+1,1024+d] + b1[d];  xt2[inputs_loc[t], d] = bf16(o1)
__global__ __launch_bounds__(256) void midk(
    const float* __restrict__ c1, const float* __restrict__ b1,
    const int* __restrict__ oloc, const int* __restrict__ iloc,
    __hip_bfloat16* __restrict__ xt2) {
  int t = blockIdx.x;
  int c = threadIdx.x * 4;
  int r = oloc[t];
  int ri = iloc[t];
  float4 a = *(const float4*)(c1 + (size_t)r * 2048 + c);
  float4 b = *(const float4*)(c1 + (size_t)(r + 1) * 2048 + 1024 + c);
  float4 bias = *(const float4*)(b1 + c);
  union { __hip_bfloat16 h[4]; uint2 u; } o;
  o.h[0] = __float2bfloat16(a.x + b.x + bias.x);
  o.h[1] = __float2bfloat16(a.y + b.y + bias.y);
  o.h[2] = __float2bfloat16(a.z + b.z + bias.z);
  o.h[3] = __float2bfloat16(a.w + b.w + bias.w);
  *(uint2*)(xt2 + (size_t)ri * 1024 + c) = o.u;
}

// ---------------- conv2 epilogue + residual + RMSNorm ----------------------
__global__ __launch_bounds__(256) void finalk(
    const float* __restrict__ c2, const float* __restrict__ x,
    const float* __restrict__ b2, const float* __restrict__ lnw,
    const int* __restrict__ oloc, float* __restrict__ out) {
  __shared__ float red[4];
  int t = blockIdx.x;
  int d = threadIdx.x * 8;
  int r = oloc[t];
  const float* p0 = c2 + (size_t)r * 4096 + d;
  const float* p1 = c2 + (size_t)(r + 1) * 4096 + 2048 + d;
  const float* pin = x + (size_t)t * 2048 + d;
  float a[8], b[8], bb[8], xi[8], o[8];
  *(float4*)&a[0] = *(const float4*)p0;       *(float4*)&a[4] = *(const float4*)(p0 + 4);
  *(float4*)&b[0] = *(const float4*)p1;       *(float4*)&b[4] = *(const float4*)(p1 + 4);
  *(float4*)&bb[0] = *(const float4*)(b2 + d); *(float4*)&bb[4] = *(const float4*)(b2 + d + 4);
  *(float4*)&xi[0] = *(const float4*)pin;     *(float4*)&xi[4] = *(const float4*)(pin + 4);
  float ss = 0.0f;
  #pragma unroll
  for (int k = 0; k < 8; ++k) {
    o[k] = a[k] + b[k] + bb[k] + xi[k];
    ss += o[k] * o[k];
  }
  #pragma unroll
  for (int off = 32; off > 0; off >>= 1) ss += __shfl_down(ss, off, 64);
  if ((threadIdx.x & 63) == 0) red[threadIdx.x >> 6] = ss;
  __syncthreads();
  float tot = red[0] + red[1] + red[2] + red[3];
  float sc = rsqrtf(tot * (1.0f / 2048.0f) + 1e-6f);
  float lw[8], res[8];
  *(float4*)&lw[0] = *(const float4*)(lnw + d); *(float4*)&lw[4] = *(const float4*)(lnw + d + 4);
  #pragma unroll
  for (int k = 0; k < 8; ++k) res[k] = o[k] * sc * lw[k];
  float* dst = out + (size_t)t * 2048 + d;
  *(float4*)dst = *(float4*)&res[0];
  *(float4*)(dst + 4) = *(float4*)&res[4];
}

extern "C" void kernel_launch(void* const* d_in, const int* in_sizes, int n_in,
                              void* d_out, int out_size, void* d_ws, size_t ws_size,
                              hipStream_t stream) {
  const float* inputs = (const float*)d_in[0];
  const int* pre_idx  = (const int*)d_in[1];
  const int* in_lf_loc = (const int*)d_in[3];
  const int* in_loc  = (const int*)d_in[5];
  const int* out_loc = (const int*)d_in[6];
  const float* lf1 = (const float*)d_in[7];
  const float* lf2 = (const float*)d_in[8];
  const float* W1 = (const float*)d_in[9];
  const float* W2 = (const float*)d_in[10];
  const float* b1 = (const float*)d_in[11];
  const float* b2 = (const float*)d_in[12];
  const float* lnw = (const float*)d_in[13];
  float* out = (float*)d_out;

  // workspace layout (c1 aliases the start of the c2 region; c1 is dead
  // before gemm2 writes c2)
  char* ws = (char*)d_ws;
  float* c2 = (float*)ws;                                    // MPAD*4096*4 = 270,532,608
  float* c1 = (float*)ws;                                    // MPAD*2048*4 (alias)
  __hip_bfloat16* xt1 = (__hip_bfloat16*)(ws + 270532608ull); // MPAD*2048*2 = 67,633,152
  __hip_bfloat16* xt2 = (__hip_bfloat16*)(ws + 338165760ull); // MPAD*1024*2 = 33,816,576
  __hip_bfloat16* w1t = (__hip_bfloat16*)(ws + 371982336ull); // 2048*2048*2
  __hip_bfloat16* w2t = (__hip_bfloat16*)(ws + 380370944ull); // 4096*1024*2

  transpose_cvt<<<dim3(N1 / 32, K1 / 32), dim3(32, 8), 0, stream>>>(W1, w1t, K1, N1);
  transpose_cvt<<<dim3(N2 / 32, K2 / 32), dim3(32, 8), 0, stream>>>(W2, w2t, K2, N2);

  scatter_tokens<<<T_TOK, 256, 0, stream>>>(inputs, in_loc, xt1);
  cachepad<<<BSQ + NPADR, 256, 0, stream>>>(lf1, pre_idx, in_lf_loc, xt1, 2048);

  gemm_bt<<<dim3(N1 / 128, MPAD / 128), 256, 0, stream>>>(xt1, w1t, c1, N1, K1);

  midk<<<T_TOK, 256, 0, stream>>>(c1, b1, out_loc, in_loc, xt2);
  cachepad<<<BSQ + NPADR, 256, 0, stream>>>(lf2, pre_idx, in_lf_loc, xt2, 1024);

  gemm_bt<<<dim3(N2 / 128, MPAD / 128), 256, 0, stream>>>(xt2, w2t, c2, N2, K2);

  finalk<<<T_TOK, 256, 0, stream>>>(c2, inputs, b2, lnw, out_loc, out);
}

// Round 2
// 691.066 us; speedup vs baseline: 1.0956x; 1.0956x over previous
//
#include <hip/hip_runtime.h>
#include <hip/hip_bf16.h>
#include <stdint.h>

// Problem constants (fixed by setup_inputs)
#define T_TOK   16384              // BS*L tokens
#define BSQ     8                  // sequences
#define MROWS   16392              // T + BS padded-buffer rows
#define D1      2048
#define D2      1024

typedef __attribute__((ext_vector_type(8))) short bf16x8;
typedef __attribute__((ext_vector_type(4))) float f32x4;

__device__ __forceinline__ void gll16(const void* g, void* l) {
  __builtin_amdgcn_global_load_lds(
      (const __attribute__((address_space(1))) void*)g,
      (__attribute__((address_space(3))) void*)l, 16, 0, 0);
}

// ---- generalized transpose+cvt: Bt[d, kout0+k] = bf16(W[k, c0+d]) ----------
// grid: (ncols/32, R/32), block (32,8)
__global__ __launch_bounds__(256) void transpose_cvt2(
    const float* __restrict__ in, __hip_bfloat16* __restrict__ out,
    int Cin, int ldout, int c0, int kout0) {
  __shared__ float tile[32][33];
  int bx = blockIdx.x * 32;   // d base
  int by = blockIdx.y * 32;   // k base
  int tx = threadIdx.x, ty = threadIdx.y;
  #pragma unroll
  for (int i = 0; i < 32; i += 8)
    tile[ty + i][tx] = in[(size_t)(by + ty + i) * Cin + c0 + bx + tx];
  __syncthreads();
  #pragma unroll
  for (int i = 0; i < 32; i += 8)
    out[(size_t)(bx + ty + i) * ldout + kout0 + by + tx] =
        __float2bfloat16(tile[tx][ty + i]);
}

// ---- scatter tokens: xt[inputs_loc[t], :] = bf16(x[t, :]), 2048 cols -------
__global__ __launch_bounds__(256) void scatter_tokens(
    const float* __restrict__ x, const int* __restrict__ loc,
    __hip_bfloat16* __restrict__ xt) {
  int t = blockIdx.x;
  int c = threadIdx.x * 8;
  int r = loc[t];
  const float* src = x + (size_t)t * 2048 + c;
  float4 v0 = *(const float4*)src;
  float4 v1 = *(const float4*)(src + 4);
  union { __hip_bfloat16 h[8]; uint4 u; } o;
  o.h[0] = __float2bfloat16(v0.x); o.h[1] = __float2bfloat16(v0.y);
  o.h[2] = __float2bfloat16(v0.z); o.h[3] = __float2bfloat16(v0.w);
  o.h[4] = __float2bfloat16(v1.x); o.h[5] = __float2bfloat16(v1.y);
  o.h[6] = __float2bfloat16(v1.z); o.h[7] = __float2bfloat16(v1.w);
  *(uint4*)(xt + (size_t)r * 2048 + c) = o.u;
}

// ---- cache rows (8 rows only — no pad rows needed in the new layout) -------
__global__ __launch_bounds__(256) void cachepad(
    const float* __restrict__ cache, const int* __restrict__ pre,
    const int* __restrict__ lfloc, __hip_bfloat16* __restrict__ xt, int cols) {
  int r = blockIdx.x;
  int dst = lfloc[r];
  const float* src = cache + (size_t)pre[r] * cols;
  for (int c = threadIdx.x; c < cols; c += 256)
    xt[(size_t)dst * cols + c] = __float2bfloat16(src[c]);
}

// ---- fused conv GEMM: K-dim folds the kernel-2 causal shift ----------------
// A-row t = concat(xt[r0+local, :], xt[r0+local+1, :]) selected by k0 < KH.
// EPI=1: write bf16(acc + bias) into padded xt2 at row t+s+1  (conv1)
// EPI=2: write f32  (acc + bias + resid[t])  into dense o3    (conv2)
template <int EPI>
__global__ __launch_bounds__(256, 2) void gemm_conv(
    const __hip_bfloat16* __restrict__ A0,
    const __hip_bfloat16* __restrict__ Bt,
    const float* __restrict__ bias,
    const float* __restrict__ resid,
    __hip_bfloat16* __restrict__ outb,
    float* __restrict__ outf,
    int N, int K, int KH, int ldA) {
  __shared__ __align__(16) __hip_bfloat16 sA[128 * 32];
  __shared__ __align__(16) __hip_bfloat16 sB[128 * 32];
  const int tid = threadIdx.x;
  const int wave = tid >> 6, lane = tid & 63;
  const int wm = wave & 1, wn = wave >> 1;
  const int tn = blockIdx.x, tm = blockIdx.y;
  const int s = tm >> 4;                       // sequence index (16 tiles/seq)
  const size_t r0 = (size_t)tm * 128 + s;      // = s*2049 + jb

  const __hip_bfloat16* A0r = A0 + r0 * ldA;         // rows r0..r0+127
  const __hip_bfloat16* A1r = A0 + (r0 + 1) * ldA;   // rows r0+1..r0+128
  const __hip_bfloat16* Bb = Bt + (size_t)tn * 128 * K;

  const int srow = wave * 16 + (lane >> 2);
  const int scol = (lane & 3) * 8;

  f32x4 acc[4][4];
  #pragma unroll
  for (int i = 0; i < 4; ++i)
    #pragma unroll
    for (int j = 0; j < 4; ++j)
      #pragma unroll
      for (int e = 0; e < 4; ++e) acc[i][j][e] = 0.0f;

  const int frow = lane & 15;
  const int fk = (lane >> 4) * 8;

  for (int k0 = 0; k0 < K; k0 += 32) {
    const __hip_bfloat16* Abase =
        (k0 < KH) ? (A0r + k0) : (A1r + (k0 - KH));
    gll16(Abase + (size_t)srow * ldA + scol,        sA + (wave * 16) * 32);
    gll16(Abase + (size_t)(64 + srow) * ldA + scol, sA + (64 + wave * 16) * 32);
    gll16(Bb + (size_t)srow * K + k0 + scol,        sB + (wave * 16) * 32);
    gll16(Bb + (size_t)(64 + srow) * K + k0 + scol, sB + (64 + wave * 16) * 32);
    __builtin_amdgcn_s_waitcnt(0);
    __syncthreads();

    bf16x8 af[4], bfr[4];
    #pragma unroll
    for (int i = 0; i < 4; ++i)
      af[i] = *(const bf16x8*)(sA + (wm * 64 + i * 16 + frow) * 32 + fk);
    #pragma unroll
    for (int j = 0; j < 4; ++j)
      bfr[j] = *(const bf16x8*)(sB + (wn * 64 + j * 16 + frow) * 32 + fk);
    #pragma unroll
    for (int i = 0; i < 4; ++i)
      #pragma unroll
      for (int j = 0; j < 4; ++j)
        acc[i][j] = __builtin_amdgcn_mfma_f32_16x16x32_bf16(af[i], bfr[j], acc[i][j], 0, 0, 0);
    __syncthreads();
  }

  const int t0 = tm * 128 + wm * 64 + (lane >> 4) * 4;  // token base
  const int ccol = tn * 128 + wn * 64 + (lane & 15);
  float bj[4];
  #pragma unroll
  for (int j = 0; j < 4; ++j) bj[j] = bias[ccol + j * 16];

  #pragma unroll
  for (int i = 0; i < 4; ++i)
    #pragma unroll
    for (int p = 0; p < 4; ++p) {
      int t = t0 + i * 16 + p;
      if (EPI == 1) {
        __hip_bfloat16* dst = outb + ((size_t)t + s + 1) * N + ccol;
        #pragma unroll
        for (int j = 0; j < 4; ++j)
          dst[j * 16] = __float2bfloat16(acc[i][j][p] + bj[j]);
      } else {
        const float* rsrc = resid + (size_t)t * N + ccol;
        float* dst = outf + (size_t)t * N + ccol;
        #pragma unroll
        for (int j = 0; j < 4; ++j)
          dst[j * 16] = acc[i][j][p] + bj[j] + rsrc[j * 16];
      }
    }
}

// ---- RMSNorm over dense o3 [16384, 2048] -----------------------------------
__global__ __launch_bounds__(256) void rmsnorm(
    const float* __restrict__ o3, const float* __restrict__ lnw,
    float* __restrict__ out) {
  __shared__ float red[4];
  int t = blockIdx.x;
  int d = threadIdx.x * 8;
  const float* p = o3 + (size_t)t * 2048 + d;
  float o[8];
  *(float4*)&o[0] = *(const float4*)p;
  *(float4*)&o[4] = *(const float4*)(p + 4);
  float ss = 0.0f;
  #pragma unroll
  for (int k = 0; k < 8; ++k) ss += o[k] * o[k];
  #pragma unroll
  for (int off = 32; off > 0; off >>= 1) ss += __shfl_down(ss, off, 64);
  if ((threadIdx.x & 63) == 0) red[threadIdx.x >> 6] = ss;
  __syncthreads();
  float tot = red[0] + red[1] + red[2] + red[3];
  float sc = rsqrtf(tot * (1.0f / 2048.0f) + 1e-6f);
  float lw[8], res[8];
  *(float4*)&lw[0] = *(const float4*)(lnw + d);
  *(float4*)&lw[4] = *(const float4*)(lnw + d + 4);
  #pragma unroll
  for (int k = 0; k < 8; ++k) res[k] = o[k] * sc * lw[k];
  float* dst = out + (size_t)t * 2048 + d;
  *(float4*)dst = *(float4*)&res[0];
  *(float4*)(dst + 4) = *(float4*)&res[4];
}

extern "C" void kernel_launch(void* const* d_in, const int* in_sizes, int n_in,
                              void* d_out, int out_size, void* d_ws, size_t ws_size,
                              hipStream_t stream) {
  const float* inputs = (const float*)d_in[0];
  const int* pre_idx  = (const int*)d_in[1];
  const int* in_lf_loc = (const int*)d_in[3];
  const int* in_loc  = (const int*)d_in[5];
  const float* lf1 = (const float*)d_in[7];
  const float* lf2 = (const float*)d_in[8];
  const float* W1 = (const float*)d_in[9];
  const float* W2 = (const float*)d_in[10];
  const float* b1 = (const float*)d_in[11];
  const float* b2 = (const float*)d_in[12];
  const float* lnw = (const float*)d_in[13];
  float* out = (float*)d_out;

  // workspace layout
  char* ws = (char*)d_ws;
  float* o3 = (float*)ws;                                     // 16384*2048*4 = 134,217,728
  __hip_bfloat16* xt1 = (__hip_bfloat16*)(ws + 134217728ull); // 16392*2048*2 = 67,141,632
  __hip_bfloat16* xt2 = (__hip_bfloat16*)(ws + 201359360ull); // 16392*1024*2 = 33,570,816
  __hip_bfloat16* bt1 = (__hip_bfloat16*)(ws + 234930176ull); // 1024*4096*2  =  8,388,608
  __hip_bfloat16* bt2 = (__hip_bfloat16*)(ws + 243318784ull); // 2048*2048*2  =  8,388,608

  // Bt1[d, k] = W1[k, d]        (k<2048)   |  W1[k-2048, 1024+d]  (k>=2048)
  transpose_cvt2<<<dim3(32, 64), dim3(32, 8), 0, stream>>>(W1, bt1, 2048, 4096, 0, 0);
  transpose_cvt2<<<dim3(32, 64), dim3(32, 8), 0, stream>>>(W1, bt1, 2048, 4096, 1024, 2048);
  // Bt2[d, k] = W2[k, d]        (k<1024)   |  W2[k-1024, 2048+d]  (k>=1024)
  transpose_cvt2<<<dim3(64, 32), dim3(32, 8), 0, stream>>>(W2, bt2, 4096, 2048, 0, 0);
  transpose_cvt2<<<dim3(64, 32), dim3(32, 8), 0, stream>>>(W2, bt2, 4096, 2048, 2048, 1024);

  scatter_tokens<<<T_TOK, 256, 0, stream>>>(inputs, in_loc, xt1);
  cachepad<<<BSQ, 256, 0, stream>>>(lf1, pre_idx, in_lf_loc, xt1, 2048);
  cachepad<<<BSQ, 256, 0, stream>>>(lf2, pre_idx, in_lf_loc, xt2, 1024);

  // conv1: M=16384, N=1024, K=4096 (KH=2048), A from xt1 (ld 2048)
  gemm_conv<1><<<dim3(8, 128), 256, 0, stream>>>(
      xt1, bt1, b1, nullptr, xt2, nullptr, 1024, 4096, 2048, 2048);

  // conv2: M=16384, N=2048, K=2048 (KH=1024), A from xt2 (ld 1024)
  gemm_conv<2><<<dim3(16, 128), 256, 0, stream>>>(
      xt2, bt2, b2, inputs, nullptr, o3, 2048, 2048, 1024, 1024);

  rmsnorm<<<T_TOK, 256, 0, stream>>>(o3, lnw, out);
}

// Round 3
// 682.623 us; speedup vs baseline: 1.1092x; 1.0124x over previous
//
#include <hip/hip_runtime.h>
#include <hip/hip_bf16.h>
#include <stdint.h>

// Problem constants (fixed by setup_inputs)
#define T_TOK   16384              // BS*L tokens
#define BSQ     8                  // sequences
#define D1      2048
#define D2      1024

typedef __attribute__((ext_vector_type(8))) short bf16x8;
typedef __attribute__((ext_vector_type(4))) float f32x4;

__device__ __forceinline__ void gll16(const void* g, void* l) {
  __builtin_amdgcn_global_load_lds(
      (const __attribute__((address_space(1))) void*)g,
      (__attribute__((address_space(3))) void*)l, 16, 0, 0);
}

// ---- all 4 weight transpose jobs in ONE launch -----------------------------
// job 0/1: W1 halves -> bt1 ; job 2/3: W2 halves -> bt2
// Each block does a 32x32 f32 tile: out[d, kout0+k] = bf16(in[k, c0+d])
__global__ __launch_bounds__(256) void transpose_all(
    const float* __restrict__ W1, const float* __restrict__ W2,
    __hip_bfloat16* __restrict__ bt1, __hip_bfloat16* __restrict__ bt2) {
  __shared__ float tile[32][33];
  int job = blockIdx.x >> 11;          // 2048 blocks per job
  int i = blockIdx.x & 2047;
  const float* in; __hip_bfloat16* out;
  int Cin, ldout, c0, kout0, bx, by;
  if (job < 2) {                       // W1: 2048x2048, halves of 1024 cols
    in = W1; out = bt1; Cin = 2048; ldout = 4096;
    c0 = job ? 1024 : 0; kout0 = job ? 2048 : 0;
    bx = (i & 31) * 32; by = (i >> 5) * 32;     // 32 x 64 tiles
  } else {                             // W2: 1024x4096, halves of 2048 cols
    in = W2; out = bt2; Cin = 4096; ldout = 2048;
    c0 = (job == 3) ? 2048 : 0; kout0 = (job == 3) ? 1024 : 0;
    bx = (i & 63) * 32; by = (i >> 6) * 32;     // 64 x 32 tiles
  }
  int tx = threadIdx.x, ty = threadIdx.y;       // (32, 8)
  #pragma unroll
  for (int q = 0; q < 32; q += 8)
    tile[ty + q][tx] = in[(size_t)(by + ty + q) * Cin + c0 + bx + tx];
  __syncthreads();
  #pragma unroll
  for (int q = 0; q < 32; q += 8)
    out[(size_t)(bx + ty + q) * ldout + kout0 + by + tx] =
        __float2bfloat16(tile[tx][ty + q]);
}

// ---- scatter tokens + both cache-row fills in ONE launch -------------------
__global__ __launch_bounds__(256) void prologue(
    const float* __restrict__ x, const int* __restrict__ loc,
    const float* __restrict__ lf1, const float* __restrict__ lf2,
    const int* __restrict__ pre, const int* __restrict__ lfloc,
    __hip_bfloat16* __restrict__ xt1, __hip_bfloat16* __restrict__ xt2) {
  int b = blockIdx.x;
  if (b < T_TOK) {
    int c = threadIdx.x * 8;
    int r = loc[b];
    const float* src = x + (size_t)b * 2048 + c;
    float4 v0 = *(const float4*)src;
    float4 v1 = *(const float4*)(src + 4);
    union { __hip_bfloat16 h[8]; uint4 u; } o;
    o.h[0] = __float2bfloat16(v0.x); o.h[1] = __float2bfloat16(v0.y);
    o.h[2] = __float2bfloat16(v0.z); o.h[3] = __float2bfloat16(v0.w);
    o.h[4] = __float2bfloat16(v1.x); o.h[5] = __float2bfloat16(v1.y);
    o.h[6] = __float2bfloat16(v1.z); o.h[7] = __float2bfloat16(v1.w);
    *(uint4*)(xt1 + (size_t)r * 2048 + c) = o.u;
  } else if (b < T_TOK + BSQ) {
    int s = b - T_TOK;
    int dst = lfloc[s];
    const float* src = lf1 + (size_t)pre[s] * 2048;
    for (int c = threadIdx.x; c < 2048; c += 256)
      xt1[(size_t)dst * 2048 + c] = __float2bfloat16(src[c]);
  } else {
    int s = b - T_TOK - BSQ;
    int dst = lfloc[s];
    const float* src = lf2 + (size_t)pre[s] * 1024;
    for (int c = threadIdx.x; c < 1024; c += 256)
      xt2[(size_t)dst * 1024 + c] = __float2bfloat16(src[c]);
  }
}

// ---- fused conv GEMM: K-dim folds the kernel-2 causal shift ----------------
// A-row t = concat(xt[r0+local, :], xt[r0+local+1, :]) — split into two clean
// K-segments so each inner loop has m97-style linear address evolution.
// EPI=1: write bf16(acc + bias) into padded xt2 at row t+s+1  (conv1)
// EPI=2: write f32  (acc + bias + resid[t])  into dense o3    (conv2)
template <int EPI>
__global__ __launch_bounds__(256, 4) void gemm_conv(
    const __hip_bfloat16* __restrict__ A0,
    const __hip_bfloat16* __restrict__ Bt,
    const float* __restrict__ bias,
    const float* __restrict__ resid,
    __hip_bfloat16* __restrict__ outb,
    float* __restrict__ outf,
    int N, int K, int KH, int ldA) {
  __shared__ __align__(16) __hip_bfloat16 sA[128 * 32];
  __shared__ __align__(16) __hip_bfloat16 sB[128 * 32];
  const int tid = threadIdx.x;
  const int wave = tid >> 6, lane = tid & 63;
  const int wm = wave & 1, wn = wave >> 1;
  const int tn = blockIdx.x, tm = blockIdx.y;
  const int s = tm >> 4;                       // sequence index (16 tiles/seq)
  const size_t r0 = (size_t)tm * 128 + s;      // = s*2049 + jb*128

  const __hip_bfloat16* Bb = Bt + (size_t)tn * 128 * K;

  const int srow = wave * 16 + (lane >> 2);
  const int scol = (lane & 3) * 8;

  f32x4 acc[4][4];
  #pragma unroll
  for (int i = 0; i < 4; ++i)
    #pragma unroll
    for (int j = 0; j < 4; ++j)
      #pragma unroll
      for (int e = 0; e < 4; ++e) acc[i][j][e] = 0.0f;

  const int frow = lane & 15;
  const int fk = (lane >> 4) * 8;

  #pragma unroll 1
  for (int seg = 0; seg < 2; ++seg) {
    const __hip_bfloat16* Ar = A0 + (r0 + seg) * ldA;   // rows r0+seg ..
    const __hip_bfloat16* Bs = Bb + seg * KH;
    #pragma unroll 1
    for (int k0 = 0; k0 < KH; k0 += 32) {
      gll16(Ar + (size_t)srow * ldA + k0 + scol,        sA + (wave * 16) * 32);
      gll16(Ar + (size_t)(64 + srow) * ldA + k0 + scol, sA + (64 + wave * 16) * 32);
      gll16(Bs + (size_t)srow * K + k0 + scol,          sB + (wave * 16) * 32);
      gll16(Bs + (size_t)(64 + srow) * K + k0 + scol,   sB + (64 + wave * 16) * 32);
      __builtin_amdgcn_s_waitcnt(0);
      __syncthreads();

      bf16x8 af[4], bfr[4];
      #pragma unroll
      for (int i = 0; i < 4; ++i)
        af[i] = *(const bf16x8*)(sA + (wm * 64 + i * 16 + frow) * 32 + fk);
      #pragma unroll
      for (int j = 0; j < 4; ++j)
        bfr[j] = *(const bf16x8*)(sB + (wn * 64 + j * 16 + frow) * 32 + fk);
      #pragma unroll
      for (int i = 0; i < 4; ++i)
        #pragma unroll
        for (int j = 0; j < 4; ++j)
          acc[i][j] = __builtin_amdgcn_mfma_f32_16x16x32_bf16(af[i], bfr[j], acc[i][j], 0, 0, 0);
      __syncthreads();
    }
  }

  const int t0 = tm * 128 + wm * 64 + (lane >> 4) * 4;  // token base
  const int ccol = tn * 128 + wn * 64 + (lane & 15);
  float bj[4];
  #pragma unroll
  for (int j = 0; j < 4; ++j) bj[j] = bias[ccol + j * 16];

  #pragma unroll
  for (int i = 0; i < 4; ++i)
    #pragma unroll
    for (int p = 0; p < 4; ++p) {
      int t = t0 + i * 16 + p;
      if (EPI == 1) {
        __hip_bfloat16* dst = outb + ((size_t)t + s + 1) * N + ccol;
        #pragma unroll
        for (int j = 0; j < 4; ++j)
          dst[j * 16] = __float2bfloat16(acc[i][j][p] + bj[j]);
      } else {
        const float* rsrc = resid + (size_t)t * N + ccol;
        float* dst = outf + (size_t)t * N + ccol;
        #pragma unroll
        for (int j = 0; j < 4; ++j)
          dst[j * 16] = acc[i][j][p] + bj[j] + rsrc[j * 16];
      }
    }
}

// ---- RMSNorm over dense o3 [16384, 2048] -----------------------------------
__global__ __launch_bounds__(256) void rmsnorm(
    const float* __restrict__ o3, const float* __restrict__ lnw,
    float* __restrict__ out) {
  __shared__ float red[4];
  int t = blockIdx.x;
  int d = threadIdx.x * 8;
  const float* p = o3 + (size_t)t * 2048 + d;
  float o[8];
  *(float4*)&o[0] = *(const float4*)p;
  *(float4*)&o[4] = *(const float4*)(p + 4);
  float ss = 0.0f;
  #pragma unroll
  for (int k = 0; k < 8; ++k) ss += o[k] * o[k];
  #pragma unroll
  for (int off = 32; off > 0; off >>= 1) ss += __shfl_down(ss, off, 64);
  if ((threadIdx.x & 63) == 0) red[threadIdx.x >> 6] = ss;
  __syncthreads();
  float tot = red[0] + red[1] + red[2] + red[3];
  float sc = rsqrtf(tot * (1.0f / 2048.0f) + 1e-6f);
  float lw[8], res[8];
  *(float4*)&lw[0] = *(const float4*)(lnw + d);
  *(float4*)&lw[4] = *(const float4*)(lnw + d + 4);
  #pragma unroll
  for (int k = 0; k < 8; ++k) res[k] = o[k] * sc * lw[k];
  float* dst = out + (size_t)t * 2048 + d;
  *(float4*)dst = *(float4*)&res[0];
  *(float4*)(dst + 4) = *(float4*)&res[4];
}

extern "C" void kernel_launch(void* const* d_in, const int* in_sizes, int n_in,
                              void* d_out, int out_size, void* d_ws, size_t ws_size,
                              hipStream_t stream) {
  const float* inputs = (const float*)d_in[0];
  const int* pre_idx  = (const int*)d_in[1];
  const int* in_lf_loc = (const int*)d_in[3];
  const int* in_loc  = (const int*)d_in[5];
  const float* lf1 = (const float*)d_in[7];
  const float* lf2 = (const float*)d_in[8];
  const float* W1 = (const float*)d_in[9];
  const float* W2 = (const float*)d_in[10];
  const float* b1 = (const float*)d_in[11];
  const float* b2 = (const float*)d_in[12];
  const float* lnw = (const float*)d_in[13];
  float* out = (float*)d_out;

  // workspace layout
  char* ws = (char*)d_ws;
  float* o3 = (float*)ws;                                     // 16384*2048*4 = 134,217,728
  __hip_bfloat16* xt1 = (__hip_bfloat16*)(ws + 134217728ull); // 16392*2048*2 = 67,141,632
  __hip_bfloat16* xt2 = (__hip_bfloat16*)(ws + 201359360ull); // 16392*1024*2 = 33,570,816
  __hip_bfloat16* bt1 = (__hip_bfloat16*)(ws + 234930176ull); // 1024*4096*2  =  8,388,608
  __hip_bfloat16* bt2 = (__hip_bfloat16*)(ws + 243318784ull); // 2048*2048*2  =  8,388,608

  transpose_all<<<8192, dim3(32, 8), 0, stream>>>(W1, W2, bt1, bt2);
  prologue<<<T_TOK + 2 * BSQ, 256, 0, stream>>>(
      inputs, in_loc, lf1, lf2, pre_idx, in_lf_loc, xt1, xt2);

  // conv1: M=16384, N=1024, K=4096 (KH=2048), A from xt1 (ld 2048)
  gemm_conv<1><<<dim3(8, 128), 256, 0, stream>>>(
      xt1, bt1, b1, nullptr, xt2, nullptr, 1024, 4096, 2048, 2048);

  // conv2: M=16384, N=2048, K=2048 (KH=1024), A from xt2 (ld 1024)
  gemm_conv<2><<<dim3(16, 128), 256, 0, stream>>>(
      xt2, bt2, b2, inputs, nullptr, o3, 2048, 2048, 1024, 1024);

  rmsnorm<<<T_TOK, 256, 0, stream>>>(o3, lnw, out);
}